// Round 3
// baseline (382.504 us; speedup 1.0000x reference)
//
#include <hip/hip_runtime.h>
#include <hip/hip_bf16.h>

#define TT 2048
#define BB 512
#define HH 32
#define NPAIR (TT * BB)
#define PSTRIDE (BB * HH)   // elements per t-slice of P = 16384
#define CSC 2.88539008177792681f   // 2*log2(e), folded into W/b/P

// Pin a value into a live VGPR (R9-proven variant, no memory clobber).
#define PIN(x) asm volatile("" : "+v"(x))

#if defined(__has_builtin)
#  if __has_builtin(__builtin_amdgcn_permlane16_swap)
#    define HAVE_PLSWAP 1
#  endif
#endif
#ifndef HAVE_PLSWAP
#  define HAVE_PLSWAP 0
#endif

// Inputs pre-scaled by CSC => tanh(u) = 1 - 2/(1+2^u'), u' = CSC*u arrives ready.
__device__ __forceinline__ float fast_tanh_pre(float u) {
    float e = exp2f(u);
    return fmaf(__builtin_amdgcn_rcpf(e + 1.0f), -2.0f, 1.0f);
}
// Unscaled variant for the fallback kernel.
__device__ __forceinline__ float fast_tanh(float u) {
    float e = exp2f(u * CSC);
    return fmaf(__builtin_amdgcn_rcpf(e + 1.0f), -2.0f, 1.0f);
}

// DPP row-rotate by N within each 16-lane row (direct ROW_ROR:N, N=1..15).
template <int N>
__device__ __forceinline__ float dpp_ror(float v) {
    return __int_as_float(__builtin_amdgcn_mov_dpp(
        __float_as_int(v), 0x120 | N, 0xF, 0xF, false));
}
// lane xor 16 within each 32-lane group (BitMode: xor=16, and=0x1F). Fallback only.
__device__ __forceinline__ float swz_x16(float v) {
    return __int_as_float(__builtin_amdgcn_ds_swizzle(__float_as_int(v), 0x401F));
}

// Un-sinkable global load: asm volatile pins the ISSUE point of the load so the
// prefetch distance (8 steps ~ >1000 cyc) is guaranteed. The matching wait is a
// counted s_waitcnt vmcnt(8) + sched_barrier(0) before first use (T14 pattern).
__device__ __forceinline__ unsigned gload_u16(const __hip_bfloat16* a) {
    unsigned r;
    asm volatile("global_load_ushort %0, %1, off" : "=v"(r) : "v"(a));
    return r;
}
#define VMWAIT8_FENCE() do { \
    asm volatile("s_waitcnt vmcnt(8)"); \
    __builtin_amdgcn_sched_barrier(0); \
} while (0)

__device__ __forceinline__ unsigned short f2bfu(float f) {
    __hip_bfloat16 h = __float2bfloat16(f);
    return *reinterpret_cast<unsigned short*>(&h);
}
__device__ __forceinline__ short f2bf(float f) {
    __hip_bfloat16 h = __float2bfloat16(f);
    return *reinterpret_cast<short*>(&h);
}

typedef __attribute__((ext_vector_type(8))) short bf16x8;
typedef __attribute__((ext_vector_type(4))) float f32x4;

// ---------------- Pass 1: MFMA precompute, swapped operands, 64 pairs/wave -------------
__global__ __launch_bounds__(256) void precompute_mfma2(
        const int* __restrict__ x, const float* __restrict__ emb,
        const float* __restrict__ W_rnn, const float* __restrict__ b_rnn,
        __hip_bfloat16* __restrict__ P) {
    const int l  = threadIdx.x & 63;
    const int wv = (blockIdx.x * 256 + threadIdx.x) >> 6;   // global wave id
    const int m16 = l & 15;
    const int q   = l >> 4;           // quad: k-slice base q*8, C-row base q*4
    const int pair0 = wv * 64;

    bf16x8 a0, a1;
#pragma unroll
    for (int j = 0; j < 8; ++j) {
        a0[j] = f2bf(CSC * W_rnn[(q * 8 + j) * HH + m16]);
        a1[j] = f2bf(CSC * W_rnn[(q * 8 + j) * HH + m16 + 16]);
    }
    f32x4 cb0, cb1;
#pragma unroll
    for (int reg = 0; reg < 4; ++reg) {
        cb0[reg] = CSC * b_rnn[q * 4 + reg];
        cb1[reg] = CSC * b_rnn[q * 4 + reg + 16];
    }

#pragma unroll
    for (int it = 0; it < 4; ++it) {
        const int pairB = pair0 + it * 16;
        const int idx = x[pairB + m16];
        const float4* ep = (const float4*)(emb + (size_t)idx * HH + q * 8);
        float4 e0 = ep[0], e1 = ep[1];
        bf16x8 bf;
        bf[0] = f2bf(e0.x); bf[1] = f2bf(e0.y); bf[2] = f2bf(e0.z); bf[3] = f2bf(e0.w);
        bf[4] = f2bf(e1.x); bf[5] = f2bf(e1.y); bf[6] = f2bf(e1.z); bf[7] = f2bf(e1.w);

        f32x4 c0 = cb0, c1 = cb1;
        c0 = __builtin_amdgcn_mfma_f32_16x16x32_bf16(a0, bf, c0, 0, 0, 0);
        c1 = __builtin_amdgcn_mfma_f32_16x16x32_bf16(a1, bf, c1, 0, 0, 0);

        uint2 s0, s1;
        s0.x = (unsigned)f2bfu(c0[0]) | ((unsigned)f2bfu(c0[1]) << 16);
        s0.y = (unsigned)f2bfu(c0[2]) | ((unsigned)f2bfu(c0[3]) << 16);
        s1.x = (unsigned)f2bfu(c1[0]) | ((unsigned)f2bfu(c1[1]) << 16);
        s1.y = (unsigned)f2bfu(c1[2]) | ((unsigned)f2bfu(c1[3]) << 16);
        __hip_bfloat16* pp = P + (size_t)(pairB + m16) * HH + q * 4;
        *(uint2*)(pp)      = s0;
        *(uint2*)(pp + 16) = s1;
    }
}

// ---------------- Pass 2: v15 — r-state full-dot, no swap on chain, asm prefetch -------
// State is r = rcp(1+2^u); h = 1-2r folded away:
//   u' = [P + CSC*rowsum(Wh)] + sum_k (-2*CSC*Wh[k][j]) * r_k
// Each lane computes its own full 32-dot from rotations of r (own 16-group) and
// rm = r[lane^16] (mirror, produced by permlane16_swap overlapped with r-side FMAs).
// Removes send-reduce + swap + select + recv-add + final fma from the serial chain.
__global__ __launch_bounds__(64, 1) void rnn_seq_v15(
        const __hip_bfloat16* __restrict__ P, const float* __restrict__ W_rnn,
        const float* __restrict__ W_cls, const float* __restrict__ b_cls,
        float* __restrict__ out) {
    const int l = threadIdx.x;
    const int i = l & 15;
    const int q = (l >> 4) & 1;
    const int j = q * 16 + i;          // == l & 31, this lane's output unit

    // Direction probe (validated R6-R14: absmax 0.0).
    int rt = __builtin_amdgcn_mov_dpp(i, 0x121, 0xF, 0xF, false);
    const int d = (rt == ((i + 1) & 15)) ? 1 : -1;

#if HAVE_PLSWAP
    // Output-order probe for permlane16_swap (per-lane select; HW-validated in v14).
    bool takeX;
    {
        unsigned lv = (unsigned)l;
        auto pr = __builtin_amdgcn_permlane16_swap(lv, lv, false, false);
        takeX = ((unsigned)pr[0] == (unsigned)(l ^ 16));
    }
#endif

    // Full weight set: w1[o] pairs with rot_o(r) (k in own 16-group),
    // w2[o] pairs with rot_o(rm) (k in other group). -2 folded in (exact).
    float w1[16], w2[16];
#pragma unroll
    for (int o = 0; o < 16; ++o) {
        const int kp = (i + d * o) & 15;
        w1[o] = -2.0f * CSC * W_rnn[(HH + q * 16 + kp) * HH + j];
        w2[o] = -2.0f * CSC * W_rnn[(HH + (q ^ 1) * 16 + kp) * HH + j];
    }
#pragma unroll
    for (int o = 0; o < 16; ++o) { PIN(w1[o]); PIN(w2[o]); }

    // WS = CSC * sum_k Wh[k][j]  (the h = 1-2r constant fold), added to p off-chain.
    float WS = 0.0f;
#pragma unroll
    for (int k = 0; k < HH; ++k) WS += W_rnn[(HH + k) * HH + j];
    WS *= CSC;

    const __hip_bfloat16* gp = P + (size_t)blockIdx.x * 64 + l;

    unsigned rA[8], rB[8];
#pragma unroll
    for (int t = 0; t < 8; ++t)
        rA[t] = gload_u16(gp + (size_t)t * PSTRIDE);

    float r = 0.5f;   // h0 = 0  =>  r0 = 0.5 everywhere (rm0 = 0.5 too)

    auto step = [&](float p) {
        // Mirror of r (lane^16). Off the critical path: consumed only by the
        // w2-side FMAs, which sit behind 16 r-side FMAs in issue order.
#if HAVE_PLSWAP
        unsigned rv = __float_as_uint(r);
        auto sw = __builtin_amdgcn_permlane16_swap(rv, rv, false, false);
        float rm = takeX ? __uint_as_float((unsigned)sw[0])
                         : __uint_as_float((unsigned)sw[1]);
#else
        float rm = swz_x16(r);
#endif
        // 8 accumulators, depth 4 each. acc0 carries p (chain start, off-chain input).
        float a0 = fmaf(r,             w1[0], p);
        float a1 = dpp_ror<1>(r)  * w1[1];
        float a2 = dpp_ror<2>(r)  * w1[2];
        float a3 = dpp_ror<3>(r)  * w1[3];
        a0 = fmaf(dpp_ror<4>(r),  w1[4],  a0);
        a1 = fmaf(dpp_ror<5>(r),  w1[5],  a1);
        a2 = fmaf(dpp_ror<6>(r),  w1[6],  a2);
        a3 = fmaf(dpp_ror<7>(r),  w1[7],  a3);
        a0 = fmaf(dpp_ror<8>(r),  w1[8],  a0);
        a1 = fmaf(dpp_ror<9>(r),  w1[9],  a1);
        a2 = fmaf(dpp_ror<10>(r), w1[10], a2);
        a3 = fmaf(dpp_ror<11>(r), w1[11], a3);
        a0 = fmaf(dpp_ror<12>(r), w1[12], a0);
        a1 = fmaf(dpp_ror<13>(r), w1[13], a1);
        a2 = fmaf(dpp_ror<14>(r), w1[14], a2);
        a3 = fmaf(dpp_ror<15>(r), w1[15], a3);

        float a4 = rm             * w2[0];
        float a5 = dpp_ror<1>(rm)  * w2[1];
        float a6 = dpp_ror<2>(rm)  * w2[2];
        float a7 = dpp_ror<3>(rm)  * w2[3];
        a4 = fmaf(dpp_ror<4>(rm),  w2[4],  a4);
        a5 = fmaf(dpp_ror<5>(rm),  w2[5],  a5);
        a6 = fmaf(dpp_ror<6>(rm),  w2[6],  a6);
        a7 = fmaf(dpp_ror<7>(rm),  w2[7],  a7);
        a4 = fmaf(dpp_ror<8>(rm),  w2[8],  a4);
        a5 = fmaf(dpp_ror<9>(rm),  w2[9],  a5);
        a6 = fmaf(dpp_ror<10>(rm), w2[10], a6);
        a7 = fmaf(dpp_ror<11>(rm), w2[11], a7);
        a4 = fmaf(dpp_ror<12>(rm), w2[12], a4);
        a5 = fmaf(dpp_ror<13>(rm), w2[13], a5);
        a6 = fmaf(dpp_ror<14>(rm), w2[14], a6);
        a7 = fmaf(dpp_ror<15>(rm), w2[15], a7);

        float u = ((a0 + a1) + (a2 + a3)) + ((a4 + a5) + (a6 + a7));
        float e = exp2f(u);
        r = __builtin_amdgcn_rcpf(e + 1.0f);
    };

#pragma unroll 1
    for (int e = 0; e < TT / 16; ++e) {
        // Issue B loads (asm: cannot sink). Outstanding: rA(8) + rB(8) = 16.
        {
            const int tB = e * 16 + 8;
#pragma unroll
            for (int t = 0; t < 8; ++t)
                rB[t] = gload_u16(gp + (size_t)(tB + t) * PSTRIDE);
        }
        VMWAIT8_FENCE();   // oldest 8 (rA) retired; rB stays in flight
        {
            float p[8];
#pragma unroll
            for (int t = 0; t < 8; ++t)
                p[t] = __uint_as_float(rA[t] << 16) + WS;   // bf16->f32 + WS fold
#pragma unroll
            for (int s = 0; s < 8; ++s) step(p[s]);
        }
        // Issue next A loads (clamped tail; extra loads harmless, never consumed).
        {
            int tA = e * 16 + 16;
            if (tA > TT - 8) tA = TT - 8;
#pragma unroll
            for (int t = 0; t < 8; ++t)
                rA[t] = gload_u16(gp + (size_t)(tA + t) * PSTRIDE);
        }
        VMWAIT8_FENCE();   // oldest 8 (rB) retired; rA' stays in flight
        {
            float p[8];
#pragma unroll
            for (int t = 0; t < 8; ++t)
                p[t] = __uint_as_float(rB[t] << 16) + WS;
#pragma unroll
            for (int s = 0; s < 8; ++s) step(p[s]);
        }
    }

    __shared__ float hf[64];
    hf[l] = fmaf(r, -2.0f, 1.0f);      // h = 1 - 2r (single wave: no barrier needed)
    if (l < 10) {
        const int rr = l / 5, c = l % 5;
        float acc = b_cls[c];
#pragma unroll
        for (int k = 0; k < 32; ++k)
            acc = fmaf(hf[rr * 32 + k], W_cls[k * 5 + c], acc);
        out[(blockIdx.x * 2 + rr) * 5 + c] = acc;
    }
}

// ---------------- Fallback (fused) for tiny workspace ----------------------------------
__device__ __forceinline__ float rnn_step_fb(const float4 xt[8], const float wx[32],
                                             const float wh[32], float bj,
                                             float* hrow, int lane) {
    float u0 = 0.f, u1 = 0.f, u2 = 0.f, u3 = 0.f;
#pragma unroll
    for (int q = 0; q < 8; ++q) {
        u0 = fmaf(xt[q].x, wx[4*q+0], u0);
        u1 = fmaf(xt[q].y, wx[4*q+1], u1);
        u2 = fmaf(xt[q].z, wx[4*q+2], u2);
        u3 = fmaf(xt[q].w, wx[4*q+3], u3);
    }
    const float4* hp = (const float4*)hrow;
#pragma unroll
    for (int q = 0; q < 8; ++q) {
        float4 hv = hp[q];
        u0 = fmaf(hv.x, wh[4*q+0], u0);
        u1 = fmaf(hv.y, wh[4*q+1], u1);
        u2 = fmaf(hv.z, wh[4*q+2], u2);
        u3 = fmaf(hv.w, wh[4*q+3], u3);
    }
    float hn = fast_tanh(bj + ((u0 + u1) + (u2 + u3)));
    hrow[lane] = hn;
    return hn;
}

__global__ __launch_bounds__(64, 1) void rnn_seq_kernel(
        const int* __restrict__ x, const float* __restrict__ emb,
        const float* __restrict__ W_rnn, const float* __restrict__ b_rnn,
        const float* __restrict__ W_cls, const float* __restrict__ b_cls,
        float* __restrict__ out) {
    const int lane = threadIdx.x & 31;
    const int grp  = threadIdx.x >> 5;
    const int row  = blockIdx.x * 2 + grp;
    __shared__ float hbuf[2][HH];
    float wx[32], wh[32];
#pragma unroll
    for (int k = 0; k < 32; ++k) {
        wx[k] = W_rnn[k * HH + lane];
        wh[k] = W_rnn[(HH + k) * HH + lane];
    }
    const float bj = b_rnn[lane];
    hbuf[grp][lane] = 0.0f;
    float* hrow = &hbuf[grp][0];
    int i1 = x[1 * BB + row];
    float4 xcur[8], xnxt[8];
    {
        int i0 = x[0 * BB + row];
        const float4* ep = (const float4*)(emb + (size_t)i0 * HH);
#pragma unroll
        for (int q = 0; q < 8; ++q) xcur[q] = ep[q];
    }
    for (int t = 0; t < TT; t += 2) {
        int i2 = x[min(t + 2, TT - 1) * BB + row];
        {
            const float4* ep = (const float4*)(emb + (size_t)i1 * HH);
#pragma unroll
            for (int q = 0; q < 8; ++q) xnxt[q] = ep[q];
        }
        rnn_step_fb(xcur, wx, wh, bj, hrow, lane);
        i1 = x[min(t + 3, TT - 1) * BB + row];
        {
            const float4* ep = (const float4*)(emb + (size_t)i2 * HH);
#pragma unroll
            for (int q = 0; q < 8; ++q) xcur[q] = ep[q];
        }
        rnn_step_fb(xnxt, wx, wh, bj, hrow, lane);
    }
    if (lane < 5) {
        float acc = b_cls[lane];
#pragma unroll
        for (int k = 0; k < 32; ++k)
            acc = fmaf(hrow[k], W_cls[k * 5 + lane], acc);
        out[row * 5 + lane] = acc;
    }
}

extern "C" void kernel_launch(void* const* d_in, const int* in_sizes, int n_in,
                              void* d_out, int out_size, void* d_ws, size_t ws_size,
                              hipStream_t stream) {
    const int*   x     = (const int*)d_in[0];
    const float* emb   = (const float*)d_in[1];
    const float* W_rnn = (const float*)d_in[2];
    const float* b_rnn = (const float*)d_in[3];
    const float* W_cls = (const float*)d_in[4];
    const float* b_cls = (const float*)d_in[5];
    float* out = (float*)d_out;

    const size_t need16 = (size_t)NPAIR * HH * 2;   // 64 MiB (bf16 P)
    if (ws_size >= need16) {
        __hip_bfloat16* P = (__hip_bfloat16*)d_ws;
        const int pre_blocks = NPAIR / 256;         // 4096 blocks x 4 waves x 64 pairs
        precompute_mfma2<<<pre_blocks, 256, 0, stream>>>(x, emb, W_rnn, b_rnn, P);
        rnn_seq_v15<<<BB / 2, 64, 0, stream>>>(P, W_rnn, W_cls, b_cls, out);
    } else {
        rnn_seq_kernel<<<BB / 2, 64, 0, stream>>>(x, emb, W_rnn, b_rnn, W_cls, b_cls, out);
    }
}

// Round 4
// 359.588 us; speedup vs baseline: 1.0637x; 1.0637x over previous
//
#include <hip/hip_runtime.h>
#include <hip/hip_bf16.h>

#define TT 2048
#define BB 512
#define HH 32
#define NPAIR (TT * BB)
#define PSTRIDE (BB * HH)   // elements per t-slice of P = 16384
#define CSC 2.88539008177792681f   // 2*log2(e), folded into W/b/P

// Pin a value into a live VGPR (R9-proven variant, no memory clobber).
#define PIN(x) asm volatile("" : "+v"(x))

#if defined(__has_builtin)
#  if __has_builtin(__builtin_amdgcn_permlane16_swap)
#    define HAVE_PLSWAP 1
#  endif
#endif
#ifndef HAVE_PLSWAP
#  define HAVE_PLSWAP 0
#endif

// Inputs pre-scaled by CSC => tanh(u) = 1 - 2/(1+2^u'), u' = CSC*u arrives ready.
__device__ __forceinline__ float fast_tanh_pre(float u) {
    float e = exp2f(u);
    return fmaf(__builtin_amdgcn_rcpf(e + 1.0f), -2.0f, 1.0f);
}
// Unscaled variant for the fallback kernel.
__device__ __forceinline__ float fast_tanh(float u) {
    float e = exp2f(u * CSC);
    return fmaf(__builtin_amdgcn_rcpf(e + 1.0f), -2.0f, 1.0f);
}

// DPP row-rotate by N within each 16-lane row (probe only).
template <int N>
__device__ __forceinline__ float dpp_ror(float v) {
    return __int_as_float(__builtin_amdgcn_mov_dpp(
        __float_as_int(v), 0x120 | N, 0xF, 0xF, false));
}
// lane xor 16 within each 32-lane group (BitMode: xor=16, and=0x1F). Fallback only.
__device__ __forceinline__ float swz_x16(float v) {
    return __int_as_float(__builtin_amdgcn_ds_swizzle(__float_as_int(v), 0x401F));
}

// Fused rotate+MAC: DPP row_ror applied to src0 of VOP2 v_fmac/v_mul.
// Removes the 15 standalone v_mov_dpp per step (v16's single change vs v14).
#define FMAC_DPP(acc, hh, ww, N) \
    asm("v_fmac_f32_dpp %0, %1, %2 row_ror:" #N " row_mask:0xf bank_mask:0xf" \
        : "+v"(acc) : "v"(hh), "v"(ww))
#define MUL_DPP(dst, hh, ww, N) \
    asm("v_mul_f32_dpp %0, %1, %2 row_ror:" #N " row_mask:0xf bank_mask:0xf" \
        : "=v"(dst) : "v"(hh), "v"(ww))

__device__ __forceinline__ unsigned short f2bfu(float f) {
    __hip_bfloat16 h = __float2bfloat16(f);
    return *reinterpret_cast<unsigned short*>(&h);
}
__device__ __forceinline__ short f2bf(float f) {
    __hip_bfloat16 h = __float2bfloat16(f);
    return *reinterpret_cast<short*>(&h);
}

typedef __attribute__((ext_vector_type(8))) short bf16x8;
typedef __attribute__((ext_vector_type(4))) float f32x4;

// ---------------- Pass 1: MFMA precompute, swapped operands, 64 pairs/wave -------------
__global__ __launch_bounds__(256) void precompute_mfma2(
        const int* __restrict__ x, const float* __restrict__ emb,
        const float* __restrict__ W_rnn, const float* __restrict__ b_rnn,
        __hip_bfloat16* __restrict__ P) {
    const int l  = threadIdx.x & 63;
    const int wv = (blockIdx.x * 256 + threadIdx.x) >> 6;   // global wave id
    const int m16 = l & 15;
    const int q   = l >> 4;           // quad: k-slice base q*8, C-row base q*4
    const int pair0 = wv * 64;

    bf16x8 a0, a1;
#pragma unroll
    for (int j = 0; j < 8; ++j) {
        a0[j] = f2bf(CSC * W_rnn[(q * 8 + j) * HH + m16]);
        a1[j] = f2bf(CSC * W_rnn[(q * 8 + j) * HH + m16 + 16]);
    }
    f32x4 cb0, cb1;
#pragma unroll
    for (int reg = 0; reg < 4; ++reg) {
        cb0[reg] = CSC * b_rnn[q * 4 + reg];
        cb1[reg] = CSC * b_rnn[q * 4 + reg + 16];
    }

#pragma unroll
    for (int it = 0; it < 4; ++it) {
        const int pairB = pair0 + it * 16;
        const int idx = x[pairB + m16];
        const float4* ep = (const float4*)(emb + (size_t)idx * HH + q * 8);
        float4 e0 = ep[0], e1 = ep[1];
        bf16x8 bf;
        bf[0] = f2bf(e0.x); bf[1] = f2bf(e0.y); bf[2] = f2bf(e0.z); bf[3] = f2bf(e0.w);
        bf[4] = f2bf(e1.x); bf[5] = f2bf(e1.y); bf[6] = f2bf(e1.z); bf[7] = f2bf(e1.w);

        f32x4 c0 = cb0, c1 = cb1;
        c0 = __builtin_amdgcn_mfma_f32_16x16x32_bf16(a0, bf, c0, 0, 0, 0);
        c1 = __builtin_amdgcn_mfma_f32_16x16x32_bf16(a1, bf, c1, 0, 0, 0);

        uint2 s0, s1;
        s0.x = (unsigned)f2bfu(c0[0]) | ((unsigned)f2bfu(c0[1]) << 16);
        s0.y = (unsigned)f2bfu(c0[2]) | ((unsigned)f2bfu(c0[3]) << 16);
        s1.x = (unsigned)f2bfu(c1[0]) | ((unsigned)f2bfu(c1[1]) << 16);
        s1.y = (unsigned)f2bfu(c1[2]) | ((unsigned)f2bfu(c1[3]) << 16);
        __hip_bfloat16* pp = P + (size_t)(pairB + m16) * HH + q * 4;
        *(uint2*)(pp)      = s0;
        *(uint2*)(pp + 16) = s1;
    }
}

// ---------------- Pass 2: v16 = v14 structure + fused DPP-FMA (no standalone rot movs) -
__global__ __launch_bounds__(64, 1) void rnn_seq_v16(
        const __hip_bfloat16* __restrict__ P, const float* __restrict__ W_rnn,
        const float* __restrict__ W_cls, const float* __restrict__ b_cls,
        float* __restrict__ out) {
    const int l = threadIdx.x;
    const int i = l & 15;
    const int q = (l >> 4) & 1;

    // Direction probe (validated R6-R15: absmax 0.0).
    int rt = __builtin_amdgcn_mov_dpp(i, 0x121, 0xF, 0xF, false);
    const int d = (rt == ((i + 1) & 15)) ? 1 : -1;

#if HAVE_PLSWAP
    // Output-order probe for permlane16_swap (per-lane select; HW-validated in v14).
    bool takeX;
    {
        unsigned lv = (unsigned)l;
        auto pr = __builtin_amdgcn_permlane16_swap(lv, lv, false, false);
        takeX = ((unsigned)pr[0] == (unsigned)(l ^ 16));
    }
#endif

    float wKeep[16], wSend[16];
#pragma unroll
    for (int o = 0; o < 16; ++o) {
        const int k = q * 16 + ((i + d * o) & 15);
        wKeep[o] = CSC * W_rnn[(HH + k) * HH + (q * 16 + i)];
        wSend[o] = CSC * W_rnn[(HH + k) * HH + ((q ^ 1) * 16 + i)];
    }
#pragma unroll
    for (int o = 0; o < 16; ++o) { PIN(wKeep[o]); PIN(wSend[o]); }

    const __hip_bfloat16* gp = P + (size_t)blockIdx.x * 64 + l;

    float pA[8], pB[8];
#pragma unroll
    for (int t = 0; t < 8; ++t)
        pA[t] = __bfloat162float(gp[(size_t)t * PSTRIDE]);

    float h = 0.0f;

    auto step = [&](float p) {
        // keep-side: 4 chains, terms o, o+4, o+8, o+12. o=0 term carries p.
        float k0 = fmaf(h, wKeep[0], p);
        float k1, k2, k3;
        MUL_DPP(k1, h, wKeep[1], 1);
        MUL_DPP(k2, h, wKeep[2], 2);
        MUL_DPP(k3, h, wKeep[3], 3);
        // send-side: 4 chains.
        float s0 = h * wSend[0];
        float s1, s2, s3;
        MUL_DPP(s1, h, wSend[1], 1);
        MUL_DPP(s2, h, wSend[2], 2);
        MUL_DPP(s3, h, wSend[3], 3);

        FMAC_DPP(k0, h, wKeep[4],  4);  FMAC_DPP(s0, h, wSend[4],  4);
        FMAC_DPP(k1, h, wKeep[5],  5);  FMAC_DPP(s1, h, wSend[5],  5);
        FMAC_DPP(k2, h, wKeep[6],  6);  FMAC_DPP(s2, h, wSend[6],  6);
        FMAC_DPP(k3, h, wKeep[7],  7);  FMAC_DPP(s3, h, wSend[7],  7);
        FMAC_DPP(k0, h, wKeep[8],  8);  FMAC_DPP(s0, h, wSend[8],  8);
        FMAC_DPP(k1, h, wKeep[9],  9);  FMAC_DPP(s1, h, wSend[9],  9);
        FMAC_DPP(k2, h, wKeep[10], 10); FMAC_DPP(s2, h, wSend[10], 10);
        FMAC_DPP(k3, h, wKeep[11], 11); FMAC_DPP(s3, h, wSend[11], 11);
        FMAC_DPP(k0, h, wKeep[12], 12); FMAC_DPP(s0, h, wSend[12], 12);
        FMAC_DPP(k1, h, wKeep[13], 13); FMAC_DPP(s1, h, wSend[13], 13);
        FMAC_DPP(k2, h, wKeep[14], 14); FMAC_DPP(s2, h, wSend[14], 14);
        FMAC_DPP(k3, h, wKeep[15], 15); FMAC_DPP(s3, h, wSend[15], 15);

        float send = (s0 + s1) + (s2 + s3);
#if HAVE_PLSWAP
        unsigned sv = __float_as_uint(send);
        auto rr = __builtin_amdgcn_permlane16_swap(sv, sv, false, false);
        float recv = takeX ? __uint_as_float((unsigned)rr[0])
                           : __uint_as_float((unsigned)rr[1]);
#else
        float recv = swz_x16(send);
#endif
        float u = ((k0 + k1) + (k2 + k3)) + recv;
        h = fast_tanh_pre(u);
    };

#pragma unroll 1
    for (int e = 0; e < TT / 16; ++e) {
        const int tB = e * 16 + 8;
#pragma unroll
        for (int t = 0; t < 8; ++t)
            pB[t] = __bfloat162float(gp[(size_t)(tB + t) * PSTRIDE]);
#pragma unroll
        for (int t = 0; t < 8; ++t) PIN(pA[t]);
#pragma unroll
        for (int s = 0; s < 8; ++s) step(pA[s]);

        int tA = e * 16 + 16;
        if (tA > TT - 8) tA = TT - 8;
#pragma unroll
        for (int t = 0; t < 8; ++t)
            pA[t] = __bfloat162float(gp[(size_t)(tA + t) * PSTRIDE]);
#pragma unroll
        for (int t = 0; t < 8; ++t) PIN(pB[t]);
#pragma unroll
        for (int s = 0; s < 8; ++s) step(pB[s]);
    }

    __shared__ float hf[64];
    hf[l] = h;
    if (l < 10) {
        const int rr = l / 5, c = l % 5;
        float acc = b_cls[c];
#pragma unroll
        for (int k = 0; k < 32; ++k)
            acc = fmaf(hf[rr * 32 + k], W_cls[k * 5 + c], acc);
        out[(blockIdx.x * 2 + rr) * 5 + c] = acc;
    }
}

// ---------------- Fallback (fused) for tiny workspace ----------------------------------
__device__ __forceinline__ float rnn_step_fb(const float4 xt[8], const float wx[32],
                                             const float wh[32], float bj,
                                             float* hrow, int lane) {
    float u0 = 0.f, u1 = 0.f, u2 = 0.f, u3 = 0.f;
#pragma unroll
    for (int q = 0; q < 8; ++q) {
        u0 = fmaf(xt[q].x, wx[4*q+0], u0);
        u1 = fmaf(xt[q].y, wx[4*q+1], u1);
        u2 = fmaf(xt[q].z, wx[4*q+2], u2);
        u3 = fmaf(xt[q].w, wx[4*q+3], u3);
    }
    const float4* hp = (const float4*)hrow;
#pragma unroll
    for (int q = 0; q < 8; ++q) {
        float4 hv = hp[q];
        u0 = fmaf(hv.x, wh[4*q+0], u0);
        u1 = fmaf(hv.y, wh[4*q+1], u1);
        u2 = fmaf(hv.z, wh[4*q+2], u2);
        u3 = fmaf(hv.w, wh[4*q+3], u3);
    }
    float hn = fast_tanh(bj + ((u0 + u1) + (u2 + u3)));
    hrow[lane] = hn;
    return hn;
}

__global__ __launch_bounds__(64, 1) void rnn_seq_kernel(
        const int* __restrict__ x, const float* __restrict__ emb,
        const float* __restrict__ W_rnn, const float* __restrict__ b_rnn,
        const float* __restrict__ W_cls, const float* __restrict__ b_cls,
        float* __restrict__ out) {
    const int lane = threadIdx.x & 31;
    const int grp  = threadIdx.x >> 5;
    const int row  = blockIdx.x * 2 + grp;
    __shared__ float hbuf[2][HH];
    float wx[32], wh[32];
#pragma unroll
    for (int k = 0; k < 32; ++k) {
        wx[k] = W_rnn[k * HH + lane];
        wh[k] = W_rnn[(HH + k) * HH + lane];
    }
    const float bj = b_rnn[lane];
    hbuf[grp][lane] = 0.0f;
    float* hrow = &hbuf[grp][0];
    int i1 = x[1 * BB + row];
    float4 xcur[8], xnxt[8];
    {
        int i0 = x[0 * BB + row];
        const float4* ep = (const float4*)(emb + (size_t)i0 * HH);
#pragma unroll
        for (int q = 0; q < 8; ++q) xcur[q] = ep[q];
    }
    for (int t = 0; t < TT; t += 2) {
        int i2 = x[min(t + 2, TT - 1) * BB + row];
        {
            const float4* ep = (const float4*)(emb + (size_t)i1 * HH);
#pragma unroll
            for (int q = 0; q < 8; ++q) xnxt[q] = ep[q];
        }
        rnn_step_fb(xcur, wx, wh, bj, hrow, lane);
        i1 = x[min(t + 3, TT - 1) * BB + row];
        {
            const float4* ep = (const float4*)(emb + (size_t)i2 * HH);
#pragma unroll
            for (int q = 0; q < 8; ++q) xcur[q] = ep[q];
        }
        rnn_step_fb(xnxt, wx, wh, bj, hrow, lane);
    }
    if (lane < 5) {
        float acc = b_cls[lane];
#pragma unroll
        for (int k = 0; k < 32; ++k)
            acc = fmaf(hrow[k], W_cls[k * 5 + lane], acc);
        out[row * 5 + lane] = acc;
    }
}

extern "C" void kernel_launch(void* const* d_in, const int* in_sizes, int n_in,
                              void* d_out, int out_size, void* d_ws, size_t ws_size,
                              hipStream_t stream) {
    const int*   x     = (const int*)d_in[0];
    const float* emb   = (const float*)d_in[1];
    const float* W_rnn = (const float*)d_in[2];
    const float* b_rnn = (const float*)d_in[3];
    const float* W_cls = (const float*)d_in[4];
    const float* b_cls = (const float*)d_in[5];
    float* out = (float*)d_out;

    const size_t need16 = (size_t)NPAIR * HH * 2;   // 64 MiB (bf16 P)
    if (ws_size >= need16) {
        __hip_bfloat16* P = (__hip_bfloat16*)d_ws;
        const int pre_blocks = NPAIR / 256;         // 4096 blocks x 4 waves x 64 pairs
        precompute_mfma2<<<pre_blocks, 256, 0, stream>>>(x, emb, W_rnn, b_rnn, P);
        rnn_seq_v16<<<BB / 2, 64, 0, stream>>>(P, W_rnn, W_cls, b_cls, out);
    } else {
        rnn_seq_kernel<<<BB / 2, 64, 0, stream>>>(x, emb, W_rnn, b_rnn, W_cls, b_cls, out);
    }
}